// Round 8
// baseline (558.095 us; speedup 1.0000x reference)
//
#include <hip/hip_runtime.h>
#include <math.h>

#define NN 8192
// out = elu(0.5*h_s + (sum_j w_ij h_n_j)/Z_i), w_ij = adj_ij * exp(relu(s_i+n_j))
// Factorization: exp(relu(s+n)) = max(exp(s)*exp(n), 1) (exp monotone) ->
// precompute es=exp(s), en=exp(n); NO transcendental in the O(N^2) loop.

typedef short short8 __attribute__((ext_vector_type(8)));   // 8 bf16 (4 VGPRs)
typedef float f32x4 __attribute__((ext_vector_type(4)));

__device__ __forceinline__ float eluf(float x) {
  return x > 0.f ? x : (__expf(x) - 1.f);
}
__device__ __forceinline__ unsigned short f2bf(float f) {
  union { float f; unsigned u; } v; v.f = f;
  unsigned r = v.u + 0x7fffu + ((v.u >> 16) & 1u);  // RNE
  return (unsigned short)(r >> 16);
}
__device__ __forceinline__ unsigned pack4(int4 v, int sh) {
  return ((unsigned)(v.x & 1) << sh) | ((unsigned)(v.y & 1) << (sh + 1)) |
         ((unsigned)(v.z & 1) << (sh + 2)) | ((unsigned)(v.w & 1) << (sh + 3));
}

// ---------------- Kernel 1: fused {projections+reductions | adj bit-pack} ----
// R7-verified. Grid 1280 x 256. Role by blockIdx%5: every 5th block streams 32
// adj rows -> bitmask P (256 blocks, HBM-bound); the rest run the proj body
// (1024 blocks, VALU-bound). Interleaved roles co-execute.
__global__ __launch_bounds__(256) void k_pre(const float* __restrict__ X,
                                             const int* __restrict__ A,
                                             const float* __restrict__ Ws,
                                             const float* __restrict__ Wn,
                                             const float* __restrict__ as_,
                                             const float* __restrict__ an_,
                                             float* __restrict__ Hs,
                                             unsigned short* __restrict__ HnT,
                                             float* __restrict__ es_out,
                                             float* __restrict__ en_out,
                                             unsigned* __restrict__ P) {
  __shared__ float4 lin4[8 * 64];  // 8 KB (proj role only)
  const int bid = blockIdx.x;
  const int q5 = bid / 5, r5 = bid - q5 * 5;
  const int t = threadIdx.x;

  if (r5 == 4) {
    // ---- pack role: rows q5*32 .. q5*32+31 -> P[row][j/32] ----
    const int row0 = q5 * 32;
#pragma unroll 1
    for (int k = 0; k < 32; ++k) {
      int g = t + k * 256;            // 0..8191
      int rr = g >> 8;                // 0..31
      int c8 = g & 255;               // word-in-row
      const int4* src = (const int4*)(A + (size_t)(row0 + rr) * NN + c8 * 32);
      int4 v0 = src[0], v1 = src[1], v2 = src[2], v3 = src[3];
      int4 v4 = src[4], v5 = src[5], v6 = src[6], v7 = src[7];
      unsigned w = pack4(v0, 0)  | pack4(v1, 4)  | pack4(v2, 8)  | pack4(v3, 12) |
                   pack4(v4, 16) | pack4(v5, 20) | pack4(v6, 24) | pack4(v7, 28);
      P[(size_t)(row0 + rr) * 256 + c8] = w;
    }
    return;
  }

  // ---- proj role (verified body): 8 rows, i0 = (q5*4+r5)*8 ----
  const int i0 = (q5 * 4 + r5) * 8;
  const float4* Xg = (const float4*)X + (size_t)i0 * 64;
  lin4[t] = Xg[t];
  lin4[t + 256] = Xg[t + 256];
  __syncthreads();
  const int c = t & 127;
  const int rh = t >> 7;  // 0..1, 4 rows each
  float accs[4], accn[4];
#pragma unroll
  for (int r = 0; r < 4; ++r) { accs[r] = 0.f; accn[r] = 0.f; }
  for (int k = 0; k < 256; k += 4) {
    float ws0 = Ws[(k + 0) * 128 + c], ws1 = Ws[(k + 1) * 128 + c];
    float ws2 = Ws[(k + 2) * 128 + c], ws3 = Ws[(k + 3) * 128 + c];
    float wn0 = Wn[(k + 0) * 128 + c], wn1 = Wn[(k + 1) * 128 + c];
    float wn2 = Wn[(k + 2) * 128 + c], wn3 = Wn[(k + 3) * 128 + c];
#pragma unroll
    for (int r = 0; r < 4; ++r) {
      float4 iv = lin4[(rh * 4 + r) * 64 + (k >> 2)];  // wave-uniform broadcast
      accs[r] = fmaf(iv.x, ws0, accs[r]); accs[r] = fmaf(iv.y, ws1, accs[r]);
      accs[r] = fmaf(iv.z, ws2, accs[r]); accs[r] = fmaf(iv.w, ws3, accs[r]);
      accn[r] = fmaf(iv.x, wn0, accn[r]); accn[r] = fmaf(iv.y, wn1, accn[r]);
      accn[r] = fmaf(iv.z, wn2, accn[r]); accn[r] = fmaf(iv.w, wn3, accn[r]);
    }
  }
  // Hs fp32 out
#pragma unroll
  for (int r = 0; r < 4; ++r)
    Hs[(size_t)(i0 + rh * 4 + r) * 128 + c] = accs[r];
  // HnT bf16 out, j-block-major: elem(jb=j/8, f, ji=j%8) at jb*1024 + f*8 + ji.
  {
    union { unsigned short us[4]; ushort4 u4; } pk;
#pragma unroll
    for (int r = 0; r < 4; ++r) pk.us[r] = f2bf(accn[r]);
    *(ushort4*)(HnT + (size_t)(i0 >> 3) * 1024 + c * 8 + rh * 4) = pk.u4;
  }
  // ---- fused reductions -> es = exp(s), en = exp(n) ----
  float* red = (float*)lin4;  // 8 x 128 f32 = 4 KB
  const int wv = t >> 6, ln = t & 63;
  __syncthreads();
  {
    float av = as_[c];
#pragma unroll
    for (int r = 0; r < 4; ++r) red[(rh * 4 + r) * 128 + c] = accs[r] * av;
  }
  __syncthreads();
#pragma unroll
  for (int h = 0; h < 2; ++h) {
    int row = wv * 2 + h;
    float p = red[row * 128 + ln] + red[row * 128 + 64 + ln];
#pragma unroll
    for (int off = 32; off >= 1; off >>= 1) p += __shfl_down(p, off);
    if (ln == 0) es_out[i0 + row] = __expf(p);
  }
  __syncthreads();
  {
    float av = an_[c];
#pragma unroll
    for (int r = 0; r < 4; ++r) red[(rh * 4 + r) * 128 + c] = accn[r] * av;
  }
  __syncthreads();
#pragma unroll
  for (int h = 0; h < 2; ++h) {
    int row = wv * 2 + h;
    float p = red[row * 128 + ln] + red[row * 128 + 64 + ln];
#pragma unroll
    for (int off = 32; off >= 1; off >>= 1) p += __shfl_down(p, off);
    if (ln == 0) en_out[i0 + row] = __expf(p);
  }
}

// ---------------- Kernel 2: attention GEMM + softmax + elu ----------------
// R5/R6-verified structure + NEW per-block j-phase STAGGER: block b starts its
// 32-step tt-loop at tt0 = (b>>3)&31 (decorrelated from XCD round-robin), so
// the 512 blocks spread over 32 phases of the shared 2 MB HnT stream instead
// of hammering identical L2 lines in lockstep. Accumulation order over j
// rotates only (fp32 acc: order-independent within tolerance). Final prefetch
// wraps to tt0 (valid, discarded) -> no workspace overrun, still branch-free.
__global__ __launch_bounds__(512, 4) void k_main(const unsigned* __restrict__ Pk,
                                                 const unsigned short* __restrict__ HnT,
                                                 const float* __restrict__ es_g,
                                                 const float* __restrict__ en_g,
                                                 float* __restrict__ HsOut) {
  __shared__ __align__(16) char smem[49152];           // 48 KB
  float* en_lds = (float*)smem;                        // 8192 f32 = 32 KB (loop)
  unsigned* bits_lds = (unsigned*)(smem + 32768);      // 4096 u32 = 16 KB (loop)
  float* cmb = (float*)smem;                           // 4*16*128 f32 = 32 KB (epilogue)
  __shared__ float zsh[8][16];
  __shared__ float zf[16];

  const int t = threadIdx.x;
  const int wv = t >> 6;   // wave 0..7 = j-partition
  const int ln = t & 63;
  const int q = ln >> 4;   // quad -> k-slice within K=32
  const int m = ln & 15;   // A row / B col / C col
  const int row0 = blockIdx.x * 16;
  const int tt0 = (blockIdx.x >> 3) & 31;  // j-phase stagger

  // ---- prologue: stage en (8192 f32) and this block's bits (16x256 u32) ----
  {
    float4* dst = (float4*)en_lds;
    const float4* s4 = (const float4*)en_g;
#pragma unroll
    for (int k = 0; k < 4; ++k) dst[t + k * 512] = s4[t + k * 512];
#pragma unroll
    for (int k = 0; k < 8; ++k) {
      int g = t + k * 512;            // 0..4095
      int rr = g >> 8;                // row-in-block 0..15
      int c8 = g & 255;               // word-in-row
      unsigned w = Pk[(size_t)(row0 + rr) * 256 + c8];
      // LDS layout [wv][tt][m]: conflict-free broadcast read per step
      bits_lds[(c8 >> 5) * 512 + (c8 & 31) * 16 + rr] = w;
    }
  }

  const float sme = es_g[row0 + m];
  // HnT elem(jb, f, ji) at jb*1024 + f*8 + ji ; lane base: jb = wv*128 + q, f = m
  const unsigned short* bptr = HnT + ((size_t)(wv * 128 + q) * 128 + m) * 8;
  const float* nvl = en_lds + wv * 1024 + q * 8;       // + tt*32
  const unsigned* bts = bits_lds + wv * 512 + m;       // + tt*16

  f32x4 acc[8];
#pragma unroll
  for (int ft = 0; ft < 8; ++ft) acc[ft] = (f32x4){0.f, 0.f, 0.f, 0.f};
  float zp = 0.f;

  union Breg { uint4 u; short8 s; };
  Breg breg[8];

  __syncthreads();  // LDS stage complete

  // breg(tt0)
  {
    const unsigned short* p = bptr + (size_t)tt0 * 4096;
    breg[0].u = *(const uint4*)(p);       breg[1].u = *(const uint4*)(p + 128);
    breg[2].u = *(const uint4*)(p + 256); breg[3].u = *(const uint4*)(p + 384);
    breg[4].u = *(const uint4*)(p + 512); breg[5].u = *(const uint4*)(p + 640);
    breg[6].u = *(const uint4*)(p + 768); breg[7].u = *(const uint4*)(p + 896);
  }

  int ttv = tt0;
#pragma unroll 2
  for (int step = 0; step < 32; ++step) {
    // ---- A-frag from LDS: w for rows m, j = wv*1024 + ttv*32 + q*8 .. +7 ----
    short8 fr;
    {
      float4 nv0 = *(const float4*)(nvl + ttv * 32);
      float4 nv1 = *(const float4*)(nvl + ttv * 32 + 4);
      const unsigned bw = bts[ttv * 16];
      const unsigned byte = (bw >> (q * 8)) & 0xffu;
      float ev[8] = {nv0.x, nv0.y, nv0.z, nv0.w, nv1.x, nv1.y, nv1.z, nv1.w};
#pragma unroll
      for (int k = 0; k < 8; ++k) {
        float w = ((byte >> k) & 1u) ? fmaxf(sme * ev[k], 1.f) : 0.f;
        zp += w;
        fr[k] = (short)f2bf(w);
      }
    }
    // ---- MFMA: consumes breg(ttv) issued last iteration ----
    __builtin_amdgcn_s_setprio(1);
    acc[0] = __builtin_amdgcn_mfma_f32_16x16x32_bf16(fr, breg[0].s, acc[0], 0, 0, 0);
    acc[1] = __builtin_amdgcn_mfma_f32_16x16x32_bf16(fr, breg[1].s, acc[1], 0, 0, 0);
    acc[2] = __builtin_amdgcn_mfma_f32_16x16x32_bf16(fr, breg[2].s, acc[2], 0, 0, 0);
    acc[3] = __builtin_amdgcn_mfma_f32_16x16x32_bf16(fr, breg[3].s, acc[3], 0, 0, 0);
    acc[4] = __builtin_amdgcn_mfma_f32_16x16x32_bf16(fr, breg[4].s, acc[4], 0, 0, 0);
    acc[5] = __builtin_amdgcn_mfma_f32_16x16x32_bf16(fr, breg[5].s, acc[5], 0, 0, 0);
    acc[6] = __builtin_amdgcn_mfma_f32_16x16x32_bf16(fr, breg[6].s, acc[6], 0, 0, 0);
    acc[7] = __builtin_amdgcn_mfma_f32_16x16x32_bf16(fr, breg[7].s, acc[7], 0, 0, 0);
    __builtin_amdgcn_s_setprio(0);
    // ---- issue breg(next), branch-free; last step wraps to tt0 (discarded) ----
    ttv = (ttv + 1) & 31;
    {
      const unsigned short* p = bptr + (size_t)ttv * 4096;
      breg[0].u = *(const uint4*)(p);       breg[1].u = *(const uint4*)(p + 128);
      breg[2].u = *(const uint4*)(p + 256); breg[3].u = *(const uint4*)(p + 384);
      breg[4].u = *(const uint4*)(p + 512); breg[5].u = *(const uint4*)(p + 640);
      breg[6].u = *(const uint4*)(p + 768); breg[7].u = *(const uint4*)(p + 896);
    }
  }

  // ---- per-wave Z partial for each row m: reduce over q ----
  {
    float zz = zp;
    zz += __shfl_down(zz, 32);
    zz += __shfl_down(zz, 16);
    if (ln < 16) zsh[wv][ln] = zz;
  }
  __syncthreads();  // all waves done reading en/bits LDS; zsh ready
  // ---- stage 1: waves 4..7 dump partials (32 KB, aliases en/bits) ----
  if (wv >= 4) {
#pragma unroll
    for (int ft = 0; ft < 8; ++ft)
#pragma unroll
      for (int reg = 0; reg < 4; ++reg)
        cmb[(wv - 4) * 2048 + (q * 4 + reg) * 128 + ft * 16 + m] = acc[ft][reg];
  }
  __syncthreads();
  // ---- stage 2: waves 0..3 accumulate partner wave's partials ----
  if (wv < 4) {
#pragma unroll
    for (int ft = 0; ft < 8; ++ft)
#pragma unroll
      for (int reg = 0; reg < 4; ++reg)
        acc[ft][reg] += cmb[wv * 2048 + (q * 4 + reg) * 128 + ft * 16 + m];
  }
  __syncthreads();
  // ---- stage 3: waves 0..3 dump combined partials ----
  if (wv < 4) {
#pragma unroll
    for (int ft = 0; ft < 8; ++ft)
#pragma unroll
      for (int reg = 0; reg < 4; ++reg)
        cmb[wv * 2048 + (q * 4 + reg) * 128 + ft * 16 + m] = acc[ft][reg];
  }
  if (t < 16) {
    float z = zsh[0][t] + zsh[1][t] + zsh[2][t] + zsh[3][t] +
              zsh[4][t] + zsh[5][t] + zsh[6][t] + zsh[7][t];
    zf[t] = 1.f / z;
  }
  __syncthreads();
  // ---- final: 4-way sum + epilogue out = elu(0.5*h_s + acc/Z) ----
  {
    const int row = t >> 5;        // 0..15
    const int f0 = (t & 31) * 4;   // 0..124
    f32x4 ssum = *(const f32x4*)&cmb[row * 128 + f0];
#pragma unroll
    for (int w = 1; w < 4; ++w) ssum += *(const f32x4*)&cmb[w * 2048 + row * 128 + f0];
    const float invz = zf[row];
    const size_t off = (size_t)(row0 + row) * 128 + f0;
    float4 h = *(const float4*)(HsOut + off);
    float4 o;
    o.x = eluf(fmaf(ssum[0], invz, 0.5f * h.x));
    o.y = eluf(fmaf(ssum[1], invz, 0.5f * h.y));
    o.z = eluf(fmaf(ssum[2], invz, 0.5f * h.z));
    o.w = eluf(fmaf(ssum[3], invz, 0.5f * h.w));
    *(float4*)(HsOut + off) = o;
  }
}

extern "C" void kernel_launch(void* const* d_in, const int* in_sizes, int n_in,
                              void* d_out, int out_size, void* d_ws, size_t ws_size,
                              hipStream_t stream) {
  const float* X   = (const float*)d_in[0];
  const int*   A   = (const int*)d_in[1];
  const float* Ws  = (const float*)d_in[2];
  const float* as_ = (const float*)d_in[3];
  const float* Wn  = (const float*)d_in[4];
  const float* an_ = (const float*)d_in[5];
  float* out = (float*)d_out;  // holds h_s, then final output (in-place epilogue)

  unsigned short* HnT = (unsigned short*)d_ws;       // 2 MB (j-block-major)
  float* es = (float*)(HnT + (size_t)128 * NN);      // 8192 f32 = exp(s)
  float* en = es + NN;                               // 8192 f32 = exp(n)
  unsigned* P = (unsigned*)(en + NN);                // 8 MB bitmask (ws is 1 GiB)

  k_pre<<<1280, 256, 0, stream>>>(X, A, Ws, Wn, as_, an_, out, HnT, es, en, P);
  k_main<<<512, 512, 0, stream>>>(P, HnT, es, en, out);
}

// Round 10
// 421.520 us; speedup vs baseline: 1.3240x; 1.3240x over previous
//
#include <hip/hip_runtime.h>
#include <math.h>

#define NN 8192
// out = elu(0.5*h_s + (sum_j w_ij h_n_j)/Z_i), w_ij = adj_ij * exp(relu(s_i+n_j))
// Factorization: exp(relu(s+n)) = max(exp(s)*exp(n), 1) (exp monotone) ->
// precompute es=exp(s), en=exp(n); NO transcendental in the O(N^2) loop.

typedef short short8 __attribute__((ext_vector_type(8)));   // 8 bf16 (4 VGPRs)
typedef float f32x4 __attribute__((ext_vector_type(4)));

__device__ __forceinline__ float eluf(float x) {
  return x > 0.f ? x : (__expf(x) - 1.f);
}
__device__ __forceinline__ unsigned short f2bf(float f) {
  union { float f; unsigned u; } v; v.f = f;
  unsigned r = v.u + 0x7fffu + ((v.u >> 16) & 1u);  // RNE
  return (unsigned short)(r >> 16);
}
__device__ __forceinline__ unsigned pack4(int4 v, int sh) {
  return ((unsigned)(v.x & 1) << sh) | ((unsigned)(v.y & 1) << (sh + 1)) |
         ((unsigned)(v.z & 1) << (sh + 2)) | ((unsigned)(v.w & 1) << (sh + 3));
}

// ---------------- Kernel 1: fused {projections+reductions | adj bit-pack} ----
// R7-verified, unchanged. Grid 1280 x 256. Role by blockIdx%5: every 5th block
// streams 32 adj rows -> bitmask P (256 blocks, HBM-bound); the rest run the
// proj body (1024 blocks, VALU-bound). Interleaved roles co-execute.
__global__ __launch_bounds__(256) void k_pre(const float* __restrict__ X,
                                             const int* __restrict__ A,
                                             const float* __restrict__ Ws,
                                             const float* __restrict__ Wn,
                                             const float* __restrict__ as_,
                                             const float* __restrict__ an_,
                                             float* __restrict__ Hs,
                                             unsigned short* __restrict__ HnT,
                                             float* __restrict__ es_out,
                                             float* __restrict__ en_out,
                                             unsigned* __restrict__ P) {
  __shared__ float4 lin4[8 * 64];  // 8 KB (proj role only)
  const int bid = blockIdx.x;
  const int q5 = bid / 5, r5 = bid - q5 * 5;
  const int t = threadIdx.x;

  if (r5 == 4) {
    const int row0 = q5 * 32;
#pragma unroll 1
    for (int k = 0; k < 32; ++k) {
      int g = t + k * 256;
      int rr = g >> 8;
      int c8 = g & 255;
      const int4* src = (const int4*)(A + (size_t)(row0 + rr) * NN + c8 * 32);
      int4 v0 = src[0], v1 = src[1], v2 = src[2], v3 = src[3];
      int4 v4 = src[4], v5 = src[5], v6 = src[6], v7 = src[7];
      unsigned w = pack4(v0, 0)  | pack4(v1, 4)  | pack4(v2, 8)  | pack4(v3, 12) |
                   pack4(v4, 16) | pack4(v5, 20) | pack4(v6, 24) | pack4(v7, 28);
      P[(size_t)(row0 + rr) * 256 + c8] = w;
    }
    return;
  }

  const int i0 = (q5 * 4 + r5) * 8;
  const float4* Xg = (const float4*)X + (size_t)i0 * 64;
  lin4[t] = Xg[t];
  lin4[t + 256] = Xg[t + 256];
  __syncthreads();
  const int c = t & 127;
  const int rh = t >> 7;
  float accs[4], accn[4];
#pragma unroll
  for (int r = 0; r < 4; ++r) { accs[r] = 0.f; accn[r] = 0.f; }
  for (int k = 0; k < 256; k += 4) {
    float ws0 = Ws[(k + 0) * 128 + c], ws1 = Ws[(k + 1) * 128 + c];
    float ws2 = Ws[(k + 2) * 128 + c], ws3 = Ws[(k + 3) * 128 + c];
    float wn0 = Wn[(k + 0) * 128 + c], wn1 = Wn[(k + 1) * 128 + c];
    float wn2 = Wn[(k + 2) * 128 + c], wn3 = Wn[(k + 3) * 128 + c];
#pragma unroll
    for (int r = 0; r < 4; ++r) {
      float4 iv = lin4[(rh * 4 + r) * 64 + (k >> 2)];
      accs[r] = fmaf(iv.x, ws0, accs[r]); accs[r] = fmaf(iv.y, ws1, accs[r]);
      accs[r] = fmaf(iv.z, ws2, accs[r]); accs[r] = fmaf(iv.w, ws3, accs[r]);
      accn[r] = fmaf(iv.x, wn0, accn[r]); accn[r] = fmaf(iv.y, wn1, accn[r]);
      accn[r] = fmaf(iv.z, wn2, accn[r]); accn[r] = fmaf(iv.w, wn3, accn[r]);
    }
  }
#pragma unroll
  for (int r = 0; r < 4; ++r)
    Hs[(size_t)(i0 + rh * 4 + r) * 128 + c] = accs[r];
  {
    union { unsigned short us[4]; ushort4 u4; } pk;
#pragma unroll
    for (int r = 0; r < 4; ++r) pk.us[r] = f2bf(accn[r]);
    *(ushort4*)(HnT + (size_t)(i0 >> 3) * 1024 + c * 8 + rh * 4) = pk.u4;
  }
  float* red = (float*)lin4;
  const int wv = t >> 6, ln = t & 63;
  __syncthreads();
  {
    float av = as_[c];
#pragma unroll
    for (int r = 0; r < 4; ++r) red[(rh * 4 + r) * 128 + c] = accs[r] * av;
  }
  __syncthreads();
#pragma unroll
  for (int h = 0; h < 2; ++h) {
    int row = wv * 2 + h;
    float p = red[row * 128 + ln] + red[row * 128 + 64 + ln];
#pragma unroll
    for (int off = 32; off >= 1; off >>= 1) p += __shfl_down(p, off);
    if (ln == 0) es_out[i0 + row] = __expf(p);
  }
  __syncthreads();
  {
    float av = an_[c];
#pragma unroll
    for (int r = 0; r < 4; ++r) red[(rh * 4 + r) * 128 + c] = accn[r] * av;
  }
  __syncthreads();
#pragma unroll
  for (int h = 0; h < 2; ++h) {
    int row = wv * 2 + h;
    float p = red[row * 128 + ln] + red[row * 128 + 64 + ln];
#pragma unroll
    for (int off = 32; off >= 1; off >>= 1) p += __shfl_down(p, off);
    if (ln == 0) en_out[i0 + row] = __expf(p);
  }
}

// ---------------- Kernel 2: attention GEMM + softmax + elu ----------------
// R9 geometry (32 rows/block, block 1024 = 2 f-halves x 8 j-parts, grid 256,
// 1 block/CU) with the epilogue layout FIXED: C-fragment mapping is
// row = q*4+reg, col = ftl*16+m (the R5-R7 verified layout) -> slot index
// g*1024 + (q*4+reg)*64 + ftl*16 + m. R9 had m as the row (blockwise
// transpose, absmax 0.259). Loop body unchanged from R9 (= R7-verified
// schedule with jp for wv): compile-time tt strides, single breg generation
// issued after the MFMA block, branch-free overrun prefetch.
__global__ __launch_bounds__(1024, 4) void k_main(const unsigned* __restrict__ Pk,
                                                  const unsigned short* __restrict__ HnT,
                                                  const float* __restrict__ es_g,
                                                  const float* __restrict__ en_g,
                                                  float* __restrict__ HsOut) {
  __shared__ __align__(16) char smem[65536];           // 64 KB
  float* en_lds = (float*)smem;                        // 8192 f32 = 32 KB (loop)
  unsigned* bits_lds = (unsigned*)(smem + 32768);      // 8192 u32 = 32 KB (loop)
  float* cmb = (float*)smem;                           // 16384 f32 (epilogue tree)
  __shared__ float zsh[8][32];
  __shared__ float zf[32];

  const int t = threadIdx.x;
  const int wv = t >> 6;     // 0..15
  const int fp = wv >> 3;    // 0..1  f-half (f-tiles fp*4 .. fp*4+3)
  const int jp = wv & 7;     // 0..7  j-partition (1024 cols each)
  const int ln = t & 63;
  const int q = ln >> 4;     // k-slice within K=32
  const int m = ln & 15;     // B col / C col (f = fp*64 + ftl*16 + m)
  const int row0 = blockIdx.x * 32;

  // ---- prologue: stage en (8192 f32) and bits for 32 rows (8192 u32) ----
  {
    float4* dst = (float4*)en_lds;
    const float4* s4 = (const float4*)en_g;
    dst[t] = s4[t];
    dst[t + 1024] = s4[t + 1024];
#pragma unroll
    for (int k = 0; k < 8; ++k) {
      int g = t + k * 1024;           // 0..8191
      int rr = g >> 8;                // row-in-block 0..31
      int c8 = g & 255;               // word-in-row (= j/32)
      unsigned w = Pk[(size_t)(row0 + rr) * 256 + c8];
      // LDS layout [jp][tt][32 rows]: broadcast-friendly loop read
      bits_lds[(c8 >> 5) * 1024 + (c8 & 31) * 32 + rr] = w;
    }
  }

  const float sme0 = es_g[row0 + m];
  const float sme1 = es_g[row0 + 16 + m];
  // HnT elem(jb, f, ji) at jb*1024 + f*8 + ji ; jb = jp*128 + q (+ tt*4),
  // f = fp*64 + ftl*16 + m
  const unsigned short* bptr = HnT + ((size_t)(jp * 128 + q) * 128 + fp * 64 + m) * 8;
  const float* nvl = en_lds + jp * 1024 + q * 8;       // + tt*32
  const unsigned* bts = bits_lds + jp * 1024 + m;      // + tt*32 (+16 for group1)

  f32x4 acc0[4], acc1[4];
#pragma unroll
  for (int ftl = 0; ftl < 4; ++ftl) {
    acc0[ftl] = (f32x4){0.f, 0.f, 0.f, 0.f};
    acc1[ftl] = (f32x4){0.f, 0.f, 0.f, 0.f};
  }
  float zp0 = 0.f, zp1 = 0.f;

  union Breg { uint4 u; short8 s; };
  Breg breg[4];

  __syncthreads();  // LDS stage complete

  // breg(0): this wave's 4 f-tiles
  breg[0].u = *(const uint4*)(bptr);
  breg[1].u = *(const uint4*)(bptr + 128);
  breg[2].u = *(const uint4*)(bptr + 256);
  breg[3].u = *(const uint4*)(bptr + 384);

#pragma unroll 2
  for (int tt = 0; tt < 32; ++tt) {
    // ---- A-frags for both row-groups: j = jp*1024 + tt*32 + q*8 .. +7 ----
    short8 fr0, fr1;
    {
      float4 nv0 = *(const float4*)(nvl + tt * 32);
      float4 nv1 = *(const float4*)(nvl + tt * 32 + 4);
      const unsigned bw0 = bts[tt * 32];        // row m
      const unsigned bw1 = bts[tt * 32 + 16];   // row m+16
      const unsigned byte0 = (bw0 >> (q * 8)) & 0xffu;
      const unsigned byte1 = (bw1 >> (q * 8)) & 0xffu;
      float ev[8] = {nv0.x, nv0.y, nv0.z, nv0.w, nv1.x, nv1.y, nv1.z, nv1.w};
#pragma unroll
      for (int k = 0; k < 8; ++k) {
        float w0 = ((byte0 >> k) & 1u) ? fmaxf(sme0 * ev[k], 1.f) : 0.f;
        float w1 = ((byte1 >> k) & 1u) ? fmaxf(sme1 * ev[k], 1.f) : 0.f;
        zp0 += w0; zp1 += w1;
        fr0[k] = (short)f2bf(w0);
        fr1[k] = (short)f2bf(w1);
      }
    }
    // ---- MFMA: 2 row-groups x 4 f-tiles share breg(tt) ----
    __builtin_amdgcn_s_setprio(1);
    acc0[0] = __builtin_amdgcn_mfma_f32_16x16x32_bf16(fr0, breg[0].s, acc0[0], 0, 0, 0);
    acc1[0] = __builtin_amdgcn_mfma_f32_16x16x32_bf16(fr1, breg[0].s, acc1[0], 0, 0, 0);
    acc0[1] = __builtin_amdgcn_mfma_f32_16x16x32_bf16(fr0, breg[1].s, acc0[1], 0, 0, 0);
    acc1[1] = __builtin_amdgcn_mfma_f32_16x16x32_bf16(fr1, breg[1].s, acc1[1], 0, 0, 0);
    acc0[2] = __builtin_amdgcn_mfma_f32_16x16x32_bf16(fr0, breg[2].s, acc0[2], 0, 0, 0);
    acc1[2] = __builtin_amdgcn_mfma_f32_16x16x32_bf16(fr1, breg[2].s, acc1[2], 0, 0, 0);
    acc0[3] = __builtin_amdgcn_mfma_f32_16x16x32_bf16(fr0, breg[3].s, acc0[3], 0, 0, 0);
    acc1[3] = __builtin_amdgcn_mfma_f32_16x16x32_bf16(fr1, breg[3].s, acc1[3], 0, 0, 0);
    __builtin_amdgcn_s_setprio(0);
    // ---- issue breg(tt+1), branch-free; tt=31 overruns <=0.2 MB into the
    // adjacent es/en/P workspace region (read-only, discarded) ----
    {
      const unsigned short* p = bptr + (size_t)(tt + 1) * 4096;  // +4 j-blocks
      breg[0].u = *(const uint4*)(p);
      breg[1].u = *(const uint4*)(p + 128);
      breg[2].u = *(const uint4*)(p + 256);
      breg[3].u = *(const uint4*)(p + 384);
    }
  }

  // ---- Z partials: w replicated across fp -> only fp==0 contributes ----
  {
    float zz0 = zp0, zz1 = zp1;
    zz0 += __shfl_down(zz0, 32); zz0 += __shfl_down(zz0, 16);
    zz1 += __shfl_down(zz1, 32); zz1 += __shfl_down(zz1, 16);
    if (fp == 0 && ln < 16) { zsh[jp][m] = zz0; zsh[jp][16 + m] = zz1; }
  }
  __syncthreads();  // loop LDS dead; zsh ready

  // ---- epilogue tree over j-partitions (slots of 2048 f32 = 32x64 tile) ----
  // C-fragment: row16 = q*4+reg, col-in-half = ftl*16+m (verified layout) ->
  // slot idx = g*1024 + (q*4+reg)*64 + ftl*16 + m
#define DUMP_SLOT(S)                                                        \
  {                                                                         \
    float* d = cmb + (S) * 2048 + q * 256 + m;                              \
    _Pragma("unroll") for (int ftl = 0; ftl < 4; ++ftl)                     \
      _Pragma("unroll") for (int reg = 0; reg < 4; ++reg) {                 \
        d[reg * 64 + ftl * 16] = acc0[ftl][reg];                            \
        d[1024 + reg * 64 + ftl * 16] = acc1[ftl][reg];                     \
      }                                                                     \
  }
#define ADD_SLOT(S)                                                         \
  {                                                                         \
    const float* d = cmb + (S) * 2048 + q * 256 + m;                        \
    _Pragma("unroll") for (int ftl = 0; ftl < 4; ++ftl)                     \
      _Pragma("unroll") for (int reg = 0; reg < 4; ++reg) {                 \
        acc0[ftl][reg] += d[reg * 64 + ftl * 16];                           \
        acc1[ftl][reg] += d[1024 + reg * 64 + ftl * 16];                    \
      }                                                                     \
  }
  // stage 1: jp 4..7 dump (8 slots, 64 KB)
  if (jp >= 4) DUMP_SLOT(fp * 4 + (jp - 4));
  __syncthreads();
  if (jp < 4) ADD_SLOT(fp * 4 + jp);
  if (t < 32) {
    float z = zsh[0][t] + zsh[1][t] + zsh[2][t] + zsh[3][t] +
              zsh[4][t] + zsh[5][t] + zsh[6][t] + zsh[7][t];
    zf[t] = 1.f / z;
  }
  __syncthreads();
  // stage 2: jp 2..3 dump (4 slots)
  if (jp == 2 || jp == 3) DUMP_SLOT(fp * 2 + (jp - 2));
  __syncthreads();
  if (jp < 2) ADD_SLOT(fp * 2 + jp);
  __syncthreads();
  // stage 3: jp==1 dump (2 slots)
  if (jp == 1) DUMP_SLOT(fp);
  __syncthreads();
  if (jp == 0) { ADD_SLOT(fp); DUMP_SLOT(fp); }  // final sums -> cmb[fp]
  __syncthreads();
#undef DUMP_SLOT
#undef ADD_SLOT

  // ---- final coalesced write: out = elu(0.5*h_s + acc/Z) ----
  {
    const int row = t >> 5;        // 0..31
    const int f0 = (t & 31) * 4;   // 0..124
    const int fpx = f0 >> 6;
    f32x4 ssum = *(const f32x4*)&cmb[fpx * 2048 + row * 64 + (f0 & 63)];
    const float invz = zf[row];
    const size_t off = (size_t)(row0 + row) * 128 + f0;
    float4 h = *(const float4*)(HsOut + off);
    float4 o;
    o.x = eluf(fmaf(ssum[0], invz, 0.5f * h.x));
    o.y = eluf(fmaf(ssum[1], invz, 0.5f * h.y));
    o.z = eluf(fmaf(ssum[2], invz, 0.5f * h.z));
    o.w = eluf(fmaf(ssum[3], invz, 0.5f * h.w));
    *(float4*)(HsOut + off) = o;
  }
}

extern "C" void kernel_launch(void* const* d_in, const int* in_sizes, int n_in,
                              void* d_out, int out_size, void* d_ws, size_t ws_size,
                              hipStream_t stream) {
  const float* X   = (const float*)d_in[0];
  const int*   A   = (const int*)d_in[1];
  const float* Ws  = (const float*)d_in[2];
  const float* as_ = (const float*)d_in[3];
  const float* Wn  = (const float*)d_in[4];
  const float* an_ = (const float*)d_in[5];
  float* out = (float*)d_out;  // holds h_s, then final output (in-place epilogue)

  unsigned short* HnT = (unsigned short*)d_ws;       // 2 MB (j-block-major)
  float* es = (float*)(HnT + (size_t)128 * NN);      // 8192 f32 = exp(s)
  float* en = es + NN;                               // 8192 f32 = exp(n)
  unsigned* P = (unsigned*)(en + NN);                // 8 MB bitmask (ws is 1 GiB)

  k_pre<<<1280, 256, 0, stream>>>(X, A, Ws, Wn, as_, an_, out, HnT, es, en, P);
  k_main<<<256, 1024, 0, stream>>>(P, HnT, es, en, out);
}